// Round 1
// baseline (86.394 us; speedup 1.0000x reference)
//
#include <hip/hip_runtime.h>

// Problem dims (fixed by reference)
#define Bb  8
#define Mm  4096
#define Nn  64
#define Ff  9
#define Ss  5
#define NRr 3

constexpr int MT     = 32;   // grid points (m) per block
constexpr int NCHUNK = 8;    // atom chunks per m
constexpr int APC    = 8;    // atoms per chunk (64/8)
constexpr int DV_PAD = 193;  // 192 floats per m-row, +1 pad -> bank-conflict-free

__global__ __launch_bounds__(256, 4)
void HarmonicGenAMD_25786983645325_kernel(
    const float* __restrict__ dv,     // [B,M,N,3]
    const float* __restrict__ coef,   // [B,N,F,3]
    const int*   __restrict__ labels, // [B,N]
    const float* __restrict__ pa,     // [S,NR]
    const float* __restrict__ pb,     // [S,NR]
    const float* __restrict__ pp,     // [S,NR]
    float*       __restrict__ out)    // [B,M]
{
    __shared__ __align__(16) float dvs[MT * DV_PAD];        // 24704 B
    __shared__ __align__(16) float atomA[Nn * Ff * 4];      // per (n,f): A, ux, uy, uz  (9216 B)
    __shared__ __align__(16) float atomR[Nn * NRr * 2];     // per (n,j): b*log2e, p     (1536 B)
    __shared__ float red[256];                              // 1024 B

    const int tid = threadIdx.x;
    const int blk = blockIdx.x;        // 0..1023
    const int b   = blk >> 7;          // / 128
    const int mt  = blk & 127;
    const int m0  = mt * MT;

    // ---- per-atom precompute into LDS (576 entries; cheap, once per block) ----
    for (int i = tid; i < Nn * Ff; i += 256) {
        const int n  = i / Ff;
        const int f  = i - n * Ff;
        const int j  = f / 3;            // radial index (repeat_interleave)
        const int s  = labels[b * Nn + n];
        const float av = pa[s * NRr + j];
        const float bv = pb[s * NRr + j];
        const float pv = pp[s * NRr + j];
        const float* c = coef + ((size_t)(b * Nn + n) * Ff + f) * 3;
        const float cx = c[0], cy = c[1], cz = c[2];
        const float cn  = __builtin_amdgcn_sqrtf(cx * cx + cy * cy + cz * cz);
        const float inv = 1.0f / fmaxf(cn, 1e-12f);
        float* d = &atomA[i * 4];
        d[0] = av * cn;       // A = a * |c|
        d[1] = cx * inv;      // unit vector
        d[2] = cy * inv;
        d[3] = cz * inv;
        if ((f - j * 3) == 0) {          // lm == 0: write radial-only entry once
            atomR[(n * NRr + j) * 2 + 0] = bv * 1.44269504088896340736f; // b*log2(e)
            atomR[(n * NRr + j) * 2 + 1] = pv;
        }
    }

    // ---- stage dv m-tile into LDS: 32 rows x 192 floats, coalesced float4 ----
    const float* g = dv + ((size_t)b * Mm + m0) * (Nn * 3);
    for (int i = tid * 4; i < MT * Nn * 3; i += 256 * 4) {
        const int row = i / 192;
        const int col = i - row * 192;
        const float4 v = *(const float4*)(g + (size_t)row * 192 + col);
        float* d = &dvs[row * DV_PAD + col];
        d[0] = v.x; d[1] = v.y; d[2] = v.z; d[3] = v.w;
    }
    __syncthreads();

    // ---- main loop: thread = (m_local, chunk of 8 atoms) ----
    const int m_local = tid & 31;
    const int chunk   = tid >> 5;
    const float* drow = &dvs[m_local * DV_PAD + chunk * (APC * 3)];

    float acc = 0.0f;
#pragma unroll
    for (int n = 0; n < APC; ++n) {
        const float x = drow[n * 3 + 0];
        const float y = drow[n * 3 + 1];
        const float z = drow[n * 3 + 2];
        const float r2   = x * x + y * y + z * z;
        const float r    = __builtin_amdgcn_sqrtf(r2);
        const float rinv = __builtin_amdgcn_rcpf(fmaxf(r, 1e-12f)); // 1/max(r,eps)
        const float l2r  = 0.5f * __builtin_amdgcn_logf(r2);        // log2(r)

        const int an = chunk * APC + n;
        const float* adA = &atomA[an * Ff * 4];
        const float* adR = &atomR[an * NRr * 2];
#pragma unroll
        for (int j = 0; j < 3; ++j) {
            const float Bc = adR[j * 2 + 0];
            const float P  = adR[j * 2 + 1];
            // a*r^p*exp(-b r) shared exponential across the 3 angular terms
            const float ek = __builtin_amdgcn_exp2f(__fmaf_rn(P, l2r, -Bc * r));
#pragma unroll
            for (int lm = 0; lm < 3; ++lm) {
                const float4 e4 = *(const float4*)&adA[(j * 3 + lm) * 4];
                const float kern = e4.x * ek;                               // A * radial
                const float cosv = (x * e4.y + y * e4.z + z * e4.w) * rinv; // dot(dv,u)/r
                float q;
                if (lm == 0)      q = cosv;                                  // P1
                else if (lm == 1) q = __fmaf_rn(1.5f * cosv, cosv, -0.5f);   // P2
                else              q = cosv * __fmaf_rn(2.5f * cosv, cosv, -1.5f); // P3
                acc = __fmaf_rn(kern, q, acc);
            }
        }
    }

    // ---- 8-way reduction over chunks, coalesced store ----
    red[tid] = acc;
    __syncthreads();
    if (tid < MT) {
        float s = 0.0f;
#pragma unroll
        for (int c = 0; c < NCHUNK; ++c) s += red[c * MT + tid];
        out[(size_t)b * Mm + m0 + tid] = s;
    }
}

extern "C" void kernel_launch(void* const* d_in, const int* in_sizes, int n_in,
                              void* d_out, int out_size, void* d_ws, size_t ws_size,
                              hipStream_t stream) {
    const float* dv   = (const float*)d_in[0];
    const float* coef = (const float*)d_in[1];
    const int*   lab  = (const int*)d_in[2];
    const float* pa   = (const float*)d_in[3];
    const float* pb   = (const float*)d_in[4];
    const float* pp   = (const float*)d_in[5];
    float* out = (float*)d_out;

    dim3 grid(Bb * (Mm / MT));  // 1024 blocks
    HarmonicGenAMD_25786983645325_kernel<<<grid, 256, 0, stream>>>(
        dv, coef, lab, pa, pb, pp, out);
}